// Round 14
// baseline (198.083 us; speedup 1.0000x reference)
//
#include <hip/hip_runtime.h>
#include <hip/hip_bf16.h>

// MultiHeadAttention: B=2, S=2048, E=1024, H=16, d=64
// bf16 MFMA (16x16x32) everywhere; fp32 softmax.
// R20: attn T15-rotation on the in-reg-P structure: per tile T,
// QK(T) [MFMA] issues before softmax+PV(T-1) [VALU+MFMA] -> intra-wave
// MFMA/VALU overlap. Two score sets sA/sB (static idx). Staging rotated:
// stage K(T+1)+V(T+1)->buf^1 after the post-SMPV barrier; entry waits
// counted vmcnt(2) (K landed, V in flight) - never 0 in loop.
// GEMMs/cast3 = R19 (measured-best 174.8us config).

#define E_DIM   1024
#define NHEADS  16
#define HDIM    64
#define SEQ     2048
#define TOK     4096          // B*S
#define QKV_DIM 3072
#define QK_STRIDE 2048        // compacted Q|K per-token row
#define QSCALE_F 0.18033688011112042f   // 0.125 * log2(e)

typedef __attribute__((ext_vector_type(8))) short bf16x8;   // 8 bf16 = 4 VGPRs
typedef __attribute__((ext_vector_type(4))) float f32x4;
typedef __attribute__((ext_vector_type(4))) int   i32x4;
typedef __attribute__((ext_vector_type(2))) int   i32x2;
typedef __attribute__((ext_vector_type(2))) __bf16 bf16x2_t;

#if __has_builtin(__builtin_amdgcn_exp2f)
#define EXP2F(x) __builtin_amdgcn_exp2f(x)
#else
#define EXP2F(x) exp2f(x)
#endif

__device__ __forceinline__ unsigned pack2bf(float a, float b) {
#if __has_builtin(__builtin_amdgcn_cvt_pk_bf16_f32)
    union { bf16x2_t v; unsigned u; } u;
    u.v = __builtin_amdgcn_cvt_pk_bf16_f32(a, b);
    return u.u;
#else
    union { float f; unsigned u; } ua, ub; ua.f = a; ub.f = b;
    unsigned ra = ua.u + 0x7FFF + ((ua.u >> 16) & 1);
    unsigned rb = ub.u + 0x7FFF + ((ub.u >> 16) & 1);
    return (ra >> 16) | (rb & 0xFFFF0000u);
#endif
}

__device__ __forceinline__ unsigned short f2bf(float x) {   // 1 VALU op
    return (unsigned short)(pack2bf(x, x) & 0xFFFFu);
}

__device__ __forceinline__ void load_lds16(const void* g, void* l) {
    __builtin_amdgcn_global_load_lds(
        (const __attribute__((address_space(1))) void*)g,
        (__attribute__((address_space(3))) void*)l, 16, 0, 0);
}

__device__ __forceinline__ bf16x8 lds_read8(const unsigned short* p) {
    union { i32x4 i; bf16x8 b; } u;
    u.i = *(const i32x4*)p;   // ds_read_b128
    return u.b;
}

__device__ __forceinline__ f32x4 mfma16(bf16x8 a, bf16x8 b, f32x4 c) {
    return __builtin_amdgcn_mfma_f32_16x16x32_bf16(a, b, c, 0, 0, 0);
}

// ---------------------------------------------------------------- fused casts
__global__ void cast3_kernel(const float* __restrict__ a, unsigned short* __restrict__ oa, int na4,
                             const float* __restrict__ b, unsigned short* __restrict__ ob, int nb4,
                             const float* __restrict__ c, unsigned short* __restrict__ oc) {
    int i = blockIdx.x * blockDim.x + threadIdx.x;
    const float* src; unsigned short* dst; int j;
    if (i < na4)            { src = a; dst = oa; j = i; }
    else if (i < na4 + nb4) { src = b; dst = ob; j = i - na4; }
    else                    { src = c; dst = oc; j = i - na4 - nb4; }
    f32x4 v = ((const f32x4*)src)[j];
    union { i32x2 i2; unsigned u[2]; } o;
    o.u[0] = pack2bf(v.x, v.y);
    o.u[1] = pack2bf(v.z, v.w);
    ((i32x2*)dst)[j] = o.i2;
}

// ---------------------------------------------------------------- GEMM1 (QKV)
// [4096,3072] = x[4096,1024] @ qkv_w^T + qkv_b, fused output routing:
//   col%192 <  64 (Q): *QSCALE -> qk[row*2048 + h*128 + part]
//   col%192 < 128 (K):          -> qk[row*2048 + h*128 + part]
//   col%192 >= 128 (V):         -> vT[bh][i][perm(s)]  (PV-slot order)
__global__ __launch_bounds__(256, 3)
void gemm_qkv_kernel(const unsigned short* __restrict__ A,
                     const unsigned short* __restrict__ B,
                     const float* __restrict__ bias,
                     unsigned short* __restrict__ qk,
                     unsigned short* __restrict__ vT,
                     int K) {
    __shared__ __align__(16) unsigned short As[128 * 64];
    __shared__ __align__(16) unsigned short Bs[128 * 64];

    const int tid  = threadIdx.x;
    const int wave = tid >> 6, lane = tid & 63;
    const int quad = lane >> 4, l16 = lane & 15;
    // XCD swizzle: 768 blocks = 8 XCDs x 96 (8 rows x 12 cols of tiles)
    const int flat = blockIdx.y * 24 + blockIdx.x;
    const int xcd = flat & 7, idx = flat >> 3;          // idx in 0..95
    const int row_blk = (xcd >> 1) * 8 + idx / 12;      // 0..31
    const int col_blk = (xcd & 1) * 12 + idx % 12;      // 0..23
    const int row0 = row_blk * 128, col0 = col_blk * 128;
    const int wr = (wave >> 1) * 64, wc = (wave & 1) * 64;

    f32x4 acc[4][4];
#pragma unroll
    for (int i = 0; i < 4; ++i)
#pragma unroll
        for (int j = 0; j < 4; ++j) acc[i][j] = (f32x4){0.f, 0.f, 0.f, 0.f};

    const int nkt = K >> 6;
    for (int kt = 0; kt < nkt; ++kt) {
        const int k0 = kt << 6;
#pragma unroll
        for (int i = 0; i < 4; ++i) {
            int p = i * 256 + tid;
            int r = p >> 3;
            int kc = (p & 7) ^ (r & 7);
            load_lds16(A + (size_t)(row0 + r) * K + k0 + kc * 8, &As[p * 8]);
        }
#pragma unroll
        for (int i = 0; i < 4; ++i) {
            int p = i * 256 + tid;
            int r = p >> 3;
            int kc = (p & 7) ^ (r & 7);
            load_lds16(B + (size_t)(col0 + r) * K + k0 + kc * 8, &Bs[p * 8]);
        }
        __syncthreads();

#pragma unroll
        for (int ks = 0; ks < 2; ++ks) {
            bf16x8 af[4], bfr[4];
#pragma unroll
            for (int rb = 0; rb < 4; ++rb) {
                int r_l  = wr + rb * 16 + l16;
                int phys = (ks * 4 + quad) ^ (l16 & 7);
                af[rb] = lds_read8(&As[r_l * 64 + phys * 8]);
            }
#pragma unroll
            for (int cb = 0; cb < 4; ++cb) {
                int r_l  = wc + cb * 16 + l16;
                int phys = (ks * 4 + quad) ^ (l16 & 7);
                bfr[cb] = lds_read8(&Bs[r_l * 64 + phys * 8]);
            }
#pragma unroll
            for (int rb = 0; rb < 4; ++rb)
#pragma unroll
                for (int cb = 0; cb < 4; ++cb)
                    acc[rb][cb] = mfma16(af[rb], bfr[cb], acc[rb][cb]);
        }
        __syncthreads();
    }

    // epilogue: C row = quad*4+reg, col = l16 (m89/m91 layout)
#pragma unroll
    for (int rb = 0; rb < 4; ++rb)
#pragma unroll
        for (int cb = 0; cb < 4; ++cb) {
            int col = col0 + wc + cb * 16 + l16;
            int h    = col / 192;
            int part = col - h * 192;
            float bv = bias[col];
            int row_b = row0 + wr + rb * 16 + quad * 4;
            float v[4];
#pragma unroll
            for (int reg = 0; reg < 4; ++reg) v[reg] = acc[rb][cb][reg] + bv;
            if (part < 128) {                  // Q or K -> qk row-major
                float sc = (part < 64) ? QSCALE_F : 1.0f;
                size_t base = (size_t)h * 128 + part;
#pragma unroll
                for (int reg = 0; reg < 4; ++reg)
                    qk[(size_t)(row_b + reg) * QK_STRIDE + base] = f2bf(v[reg] * sc);
            } else {                           // V -> vT[bh][i][perm(s)], 8B packed
                int i  = part - 128;
                int b  = row_b >> 11;
                int s0 = row_b & 2047;
                // key-permutation within 128-tile: slot=(c>>1)*32+q*8+(c&1)*4+r
                int kk = s0 & 127;
                int cc = kk >> 4, qq = (kk >> 2) & 3;
                int sp = (s0 & ~127) | ((cc >> 1) << 5) | (qq << 3) | ((cc & 1) << 2);
                i32x2 pk;
                pk.x = (int)pack2bf(v[0], v[1]);
                pk.y = (int)pack2bf(v[2], v[3]);
                *(i32x2*)&vT[(((size_t)(b * 16 + h)) * 64 + i) * SEQ + sp] = pk;
            }
        }
}

// ---------------------------------------------------------------- GEMM2 128x64
// out[4096,1024] = attn @ out_w^T + out_b.  512 blocks = 2/CU exact.
__global__ __launch_bounds__(256, 2)
void gemm2_kernel(const unsigned short* __restrict__ A,
                  const unsigned short* __restrict__ B,
                  const float* __restrict__ bias,
                  float* __restrict__ C, int M, int N, int K) {
    __shared__ __align__(16) unsigned short As[128 * 64];   // 16KB
    __shared__ __align__(16) unsigned short Bs[64 * 64];    //  8KB

    const int tid  = threadIdx.x;
    const int wave = tid >> 6, lane = tid & 63;
    const int quad = lane >> 4, l16 = lane & 15;
    // XCD swizzle: 512 blocks = 8 XCDs x 64 (8 rows x 8 cols of tiles)
    const int flat = blockIdx.y * 16 + blockIdx.x;
    const int xcd = flat & 7, idx = flat >> 3;          // idx in 0..63
    const int row_blk = (xcd >> 1) * 8 + (idx >> 3);    // 0..31
    const int col_blk = (xcd & 1) * 8 + (idx & 7);      // 0..15
    const int row0 = row_blk * 128, col0 = col_blk * 64;
    const int wr = wave * 32;

    f32x4 acc[2][4];
#pragma unroll
    for (int i = 0; i < 2; ++i)
#pragma unroll
        for (int j = 0; j < 4; ++j) acc[i][j] = (f32x4){0.f, 0.f, 0.f, 0.f};

    const int nkt = K >> 6;
    for (int kt = 0; kt < nkt; ++kt) {
        const int k0 = kt << 6;
#pragma unroll
        for (int i = 0; i < 4; ++i) {
            int p = i * 256 + tid;
            int r = p >> 3;
            int kc = (p & 7) ^ (r & 7);
            load_lds16(A + (size_t)(row0 + r) * K + k0 + kc * 8, &As[p * 8]);
        }
#pragma unroll
        for (int i = 0; i < 2; ++i) {
            int p = i * 256 + tid;
            int r = p >> 3;
            int kc = (p & 7) ^ (r & 7);
            load_lds16(B + (size_t)(col0 + r) * K + k0 + kc * 8, &Bs[p * 8]);
        }
        __syncthreads();

#pragma unroll
        for (int ks = 0; ks < 2; ++ks) {
            bf16x8 af[2], bfr[4];
#pragma unroll
            for (int rb = 0; rb < 2; ++rb) {
                int r_l  = wr + rb * 16 + l16;
                int phys = (ks * 4 + quad) ^ (l16 & 7);
                af[rb] = lds_read8(&As[r_l * 64 + phys * 8]);
            }
#pragma unroll
            for (int cb = 0; cb < 4; ++cb) {
                int r_l  = cb * 16 + l16;
                int phys = (ks * 4 + quad) ^ (l16 & 7);
                bfr[cb] = lds_read8(&Bs[r_l * 64 + phys * 8]);
            }
#pragma unroll
            for (int rb = 0; rb < 2; ++rb)
#pragma unroll
                for (int cb = 0; cb < 4; ++cb)
                    acc[rb][cb] = mfma16(af[rb], bfr[cb], acc[rb][cb]);
        }
        __syncthreads();
    }

#pragma unroll
    for (int rb = 0; rb < 2; ++rb)
#pragma unroll
        for (int cb = 0; cb < 4; ++cb) {
            int col = col0 + cb * 16 + l16;
            float bv = bias[col];
#pragma unroll
            for (int reg = 0; reg < 4; ++reg) {
                int row = row0 + wr + rb * 16 + quad * 4 + reg;
                C[(size_t)row * N + col] = acc[rb][cb][reg] + bv;
            }
        }
}

// ---------------------------------------------------------------- attention
// R20: T15 rotation. Per tile T: [vmcnt(2); bar] -> QK(T) [MFMA] ->
// SMPV(T-1) [exp+PV, overlaps QK latency] -> bar -> stage K,V(T+1).
// In-reg P (V-key-permute), two score sets sA/sB, counted vmcnt.

#define STAGE_K(BUF) do {                                                      \
    load_lds16(kg[0], lk[0] + (BUF) * 8192); kg[0] += 128 * QK_STRIDE;         \
    load_lds16(kg[1], lk[1] + (BUF) * 8192); kg[1] += 128 * QK_STRIDE;         \
} while (0)
#define STAGE_V(BUF) do {                                                      \
    load_lds16(vg[0], lv[0] + (BUF) * 8192); vg[0] += 128;                     \
    load_lds16(vg[1], lv[1] + (BUF) * 8192); vg[1] += 128;                     \
} while (0)

// QK of one 128-key tile: scores into S (8 x f32x4), K from buf BUF
#define QK_TILE(S, BUF) do {                                                   \
    constexpr int KO_ = (BUF) * 8192;                                          \
    _Pragma("unroll") for (int cb = 0; cb < 8; ++cb)                           \
        S[cb] = (f32x4){0.f, 0.f, 0.f, 0.f};                                   \
    __builtin_amdgcn_s_setprio(1);                                             \
    _Pragma("unroll") for (int cb = 0; cb < 8; ++cb) {                         \
        bf16x8 kf0 = lds_read8(Kb0 + KO_ + cb * 1024);                         \
        S[cb] = mfma16(kf0, qf[0], S[cb]);                                     \
    }                                                                          \
    _Pragma("unroll") for (int cb = 0; cb < 8; ++cb) {                         \
        bf16x8 kf1 = lds_read8(Kb1 + KO_ + cb * 1024);                         \
        S[cb] = mfma16(kf1, qf[1], S[cb]);                                     \
    }                                                                          \
    __builtin_amdgcn_s_setprio(0);                                             \
} while (0)

// softmax numerator + PV for scores S, V in buf BUF (in-register P)
#define SMPV_TILE(S, BUF) do {                                                 \
    constexpr int KO_ = (BUF) * 8192;                                          \
    _Pragma("unroll") for (int cb = 0; cb < 8; ++cb)                           \
        _Pragma("unroll") for (int r = 0; r < 4; ++r)                          \
            S[cb][r] = EXP2F(S[cb][r]);                                        \
    {                                                                          \
        f32x4 t0 = S[0] + S[1], t1 = S[2] + S[3];                              \
        f32x4 t2 = S[4] + S[5], t3 = S[6] + S[7];                              \
        t0 += t1; t2 += t3;                                                    \
        lsum += t0 + t2;                                                       \
    }                                                                          \
    __builtin_amdgcn_s_setprio(1);                                             \
    _Pragma("unroll") for (int ks2 = 0; ks2 < 4; ++ks2) {                      \
        union { i32x4 i; bf16x8 b; } pu;                                       \
        pu.i.x = (int)pack2bf(S[2 * ks2][0], S[2 * ks2][1]);                   \
        pu.i.y = (int)pack2bf(S[2 * ks2][2], S[2 * ks2][3]);                   \
        pu.i.z = (int)pack2bf(S[2 * ks2 + 1][0], S[2 * ks2 + 1][1]);           \
        pu.i.w = (int)pack2bf(S[2 * ks2 + 1][2], S[2 * ks2 + 1][3]);           \
        bf16x8 pf = pu.b;                                                      \
        _Pragma("unroll") for (int ib = 0; ib < 4; ++ib) {                     \
            bf16x8 vf = lds_read8(Vb[ks2] + KO_ + ib * 2048);                  \
            o[ib] = mfma16(pf, vf, o[ib]);                                     \
        }                                                                      \
    }                                                                          \
    __builtin_amdgcn_s_setprio(0);                                             \
} while (0)

// one rotated iteration for tile T: CUR = T&1. QK(T) then SMPV(T-1).
#define ATTN_ITER(SC, SP, CUR) do {                                            \
    __asm__ volatile("s_waitcnt vmcnt(2)" ::: "memory");                       \
    __builtin_amdgcn_s_barrier();                                              \
    QK_TILE(SC, CUR);                                                          \
    SMPV_TILE(SP, (CUR) ^ 1);                                                  \
    __builtin_amdgcn_s_barrier();                                              \
    STAGE_K((CUR) ^ 1);                                                        \
    STAGE_V((CUR) ^ 1);                                                        \
} while (0)

__global__ __launch_bounds__(512, 4)
void attn_kernel(const unsigned short* __restrict__ qk,
                 const unsigned short* __restrict__ vT,
                 unsigned short* __restrict__ attn) {
    __shared__ __align__(16) unsigned short Ks[2][128 * 64]; // 32KB [buf][key][dim]
    __shared__ __align__(16) unsigned short Vs[2][64 * 128]; // 32KB [buf][i][slot]

    const int tid  = threadIdx.x;
    const int wave = tid >> 6, lane = tid & 63;
    const int quad = lane >> 4, l16 = lane & 15;

    // T1: XCD-aware remap (R9-proven).
    const int flat = blockIdx.y * 16 + blockIdx.x;
    const int swz  = (flat & 7) * 64 + (flat >> 3);
    const int bh = swz >> 4;
    const int b = bh >> 4, h = bh & 15;
    const int q0 = (swz & 15) * 128;
    const size_t rowbase = (size_t)b * SEQ;
    const int qtok = q0 + wave * 16 + l16;

    // per-lane LDS bases (shorts); loop vars become immediate offsets
    const int sw3 = l16 & 7;
    const unsigned short* Kb0 = &Ks[0][l16 * 64 + ((quad ^ sw3) * 8)];         // ks=0, +cb*1024
    const unsigned short* Kb1 = &Ks[0][l16 * 64 + (((4 + quad) ^ sw3) * 8)];   // ks=1
    const unsigned short* Vb[4] = {                                            // ks2=0..3, +ib*2048
        &Vs[0][l16 * 128 + (((0 * 4 + quad) ^ l16) * 8)],
        &Vs[0][l16 * 128 + (((1 * 4 + quad) ^ l16) * 8)],
        &Vs[0][l16 * 128 + (((2 * 4 + quad) ^ l16) * 8)],
        &Vs[0][l16 * 128 + (((3 * 4 + quad) ^ l16) * 8)] };

    // staging addresses (hoisted; advance by constant per tile)
    const unsigned short* kg[2]; unsigned short* lk[2];
    const unsigned short* vg[2]; unsigned short* lv[2];
#pragma unroll
    for (int i = 0; i < 2; ++i) {
        int p = i * 512 + tid;
        { int r = p >> 3; int kc = (p & 7) ^ (r & 7);
          kg[i] = qk + (rowbase) * QK_STRIDE + h * 128 + 64 + (size_t)r * QK_STRIDE + kc * 8;
          lk[i] = &Ks[0][p * 8]; }
        { int r = p >> 4; int c = (p & 15) ^ (r & 15);
          vg[i] = vT + (size_t)bh * 64 * SEQ + (size_t)r * SEQ + c * 8;
          lv[i] = &Vs[0][p * 8]; }
    }

    // Q fragments (B-operand: n=l16=query, k=quad*8+j), pre-scaled in GEMM1
    bf16x8 qf[2];
#pragma unroll
    for (int ks = 0; ks < 2; ++ks) {
        const unsigned short* p =
            qk + (rowbase + qtok) * QK_STRIDE + h * 128 + ks * 32 + quad * 8;
        union { i32x4 i; bf16x8 b; } u;
        u.i = *(const i32x4*)p;
        qf[ks] = u.b;
    }

    f32x4 o[4];
#pragma unroll
    for (int ib = 0; ib < 4; ++ib) o[ib] = (f32x4){0.f, 0.f, 0.f, 0.f};
    f32x4 lsum = (f32x4){0.f, 0.f, 0.f, 0.f};

    f32x4 sA[8], sB[8];

    // ---- prologue: stage tiles 0,1; QK(0)
    STAGE_K(0); STAGE_V(0);          // tile 0 -> buf0
    STAGE_K(1); STAGE_V(1);          // tile 1 -> buf1
    __asm__ volatile("s_waitcnt vmcnt(4)" ::: "memory");  // tile 0 landed
    __builtin_amdgcn_s_barrier();
    QK_TILE(sA, 0);

    // ---- rotated loop: tiles 1..14 (7 pairs), SMPV lags QK by one tile
#pragma unroll 1
    for (int kt = 1; kt < 15; kt += 2) {
        ATTN_ITER(sB, sA, 1);   // T=kt   : QK->sB (buf1); SMPV(T-1, buf0); stage T+1->buf0
        ATTN_ITER(sA, sB, 0);   // T=kt+1 : QK->sA (buf0); SMPV(T-1, buf1); stage T+1->buf1
    }

    // ---- tile 15: QK + SMPV(14); no stage; then SMPV(15)
    __asm__ volatile("s_waitcnt vmcnt(2)" ::: "memory");
    __builtin_amdgcn_s_barrier();
    QK_TILE(sB, 1);
    SMPV_TILE(sA, 0);            // tile 14 (V in buf0)
    __asm__ volatile("s_waitcnt vmcnt(0)" ::: "memory");
    __builtin_amdgcn_s_barrier();
    SMPV_TILE(sB, 1);            // tile 15 (V in buf1)

    // ---- softmax denominator: horizontal + cross-quad reduce (once)
    float l_p = (lsum[0] + lsum[1]) + (lsum[2] + lsum[3]);
    l_p += __shfl_xor(l_p, 16);
    l_p += __shfl_xor(l_p, 32);

    // ---- normalize, write attn[token][h*64+i] (bf16). O rows = quad*4+r.
    float il[4];
#pragma unroll
    for (int r = 0; r < 4; ++r) il[r] = 1.0f / __shfl(l_p, quad * 4 + r);
#pragma unroll
    for (int ib = 0; ib < 4; ++ib)
#pragma unroll
        for (int r = 0; r < 4; ++r) {
            int t = q0 + wave * 16 + quad * 4 + r;
            attn[(rowbase + t) * E_DIM + h * 64 + ib * 16 + l16] =
                f2bf(o[ib][r] * il[r]);
        }
}

// ---------------------------------------------------------------- launch
extern "C" void kernel_launch(void* const* d_in, const int* in_sizes, int n_in,
                              void* d_out, int out_size, void* d_ws, size_t ws_size,
                              hipStream_t stream) {
    const float* x     = (const float*)d_in[0];   // [2,2048,1024]
    const float* qkv_w = (const float*)d_in[1];   // [3072,1024]
    const float* qkv_b = (const float*)d_in[2];   // [3072]
    const float* out_w = (const float*)d_in[3];   // [1024,1024]
    const float* out_b = (const float*)d_in[4];   // [1024]

    char* ws = (char*)d_ws;
    unsigned short* xb   = (unsigned short*)(ws);               //  8 MB
    unsigned short* wqkv = (unsigned short*)(ws + 8388608);     //  6 MB
    unsigned short* wout = (unsigned short*)(ws + 14680064);    //  2 MB
    unsigned short* qk   = (unsigned short*)(ws + 16777216);    // 16 MB [4096][2048]
    unsigned short* attn = (unsigned short*)(ws + 33554432);    //  8 MB
    unsigned short* vT   = (unsigned short*)(ws + 41943040);    //  8 MB [32][64][2048]
    // total 48 MB

    // fused casts: x (1048576 f32x4), qkv_w (786432), out_w (262144)
    cast3_kernel<<<8192, 256, 0, stream>>>(x, xb, 1048576,
                                           qkv_w, wqkv, 786432,
                                           out_w, wout);

    // QKV projection with fused routing: Q,K -> qk (Q scaled); V -> vT (permuted)
    gemm_qkv_kernel<<<dim3(24, 32), 256, 0, stream>>>(
        xb, wqkv, qkv_b, qk, vT, E_DIM);

    // flash attention -> attn [4096, 1024] bf16 (128q/512thr, T15 rotation)
    attn_kernel<<<dim3(16, 32), 512, 0, stream>>>(qk, vT, attn);

    // out = attn @ out_w^T + out_b   [4096, 1024] fp32 (128x64 tiles, 512 blocks)
    gemm2_kernel<<<dim3(16, 32), 256, 0, stream>>>(
        attn, wout, out_b, (float*)d_out, TOK, E_DIM, E_DIM);
}

// Round 15
// 170.996 us; speedup vs baseline: 1.1584x; 1.1584x over previous
//
#include <hip/hip_runtime.h>
#include <hip/hip_bf16.h>

// MultiHeadAttention: B=2, S=2048, E=1024, H=16, d=64
// bf16 MFMA (16x16x32) everywhere; fp32 softmax.
// R21 = R19 (measured-best 174.8us). R20's T15 rotation reverted: the
// second score set spilled to scratch under the 128-VGPR cap
// (WRITE_SIZE 8->39MB), attn 50.5->67.6us. Final configuration:
//  - cast3: fused f32->bf16 casts (x, qkv_w, out_w)
//  - gemm_qkv: 128x128, 3 blocks/CU, XCD-chunked swizzle, fused routing
//    (Q scaled into qk; K into qk; V pre-permuted into vT for in-reg P)
//  - attn: 128q/512thr, swapped QK^T, in-register P (zero bank
//    conflicts), K/V double-buffer + counted vmcnt(4), hoisted softmax
//    denominator, XCD swizzle
//  - gemm2: 128x64, 2 blocks/CU, XCD-chunked swizzle

#define E_DIM   1024
#define NHEADS  16
#define HDIM    64
#define SEQ     2048
#define TOK     4096          // B*S
#define QKV_DIM 3072
#define QK_STRIDE 2048        // compacted Q|K per-token row
#define QSCALE_F 0.18033688011112042f   // 0.125 * log2(e)

typedef __attribute__((ext_vector_type(8))) short bf16x8;   // 8 bf16 = 4 VGPRs
typedef __attribute__((ext_vector_type(4))) float f32x4;
typedef __attribute__((ext_vector_type(4))) int   i32x4;
typedef __attribute__((ext_vector_type(2))) int   i32x2;
typedef __attribute__((ext_vector_type(2))) __bf16 bf16x2_t;

#if __has_builtin(__builtin_amdgcn_exp2f)
#define EXP2F(x) __builtin_amdgcn_exp2f(x)
#else
#define EXP2F(x) exp2f(x)
#endif

__device__ __forceinline__ unsigned pack2bf(float a, float b) {
#if __has_builtin(__builtin_amdgcn_cvt_pk_bf16_f32)
    union { bf16x2_t v; unsigned u; } u;
    u.v = __builtin_amdgcn_cvt_pk_bf16_f32(a, b);
    return u.u;
#else
    union { float f; unsigned u; } ua, ub; ua.f = a; ub.f = b;
    unsigned ra = ua.u + 0x7FFF + ((ua.u >> 16) & 1);
    unsigned rb = ub.u + 0x7FFF + ((ub.u >> 16) & 1);
    return (ra >> 16) | (rb & 0xFFFF0000u);
#endif
}

__device__ __forceinline__ unsigned short f2bf(float x) {   // 1 VALU op
    return (unsigned short)(pack2bf(x, x) & 0xFFFFu);
}

__device__ __forceinline__ void load_lds16(const void* g, void* l) {
    __builtin_amdgcn_global_load_lds(
        (const __attribute__((address_space(1))) void*)g,
        (__attribute__((address_space(3))) void*)l, 16, 0, 0);
}

__device__ __forceinline__ bf16x8 lds_read8(const unsigned short* p) {
    union { i32x4 i; bf16x8 b; } u;
    u.i = *(const i32x4*)p;   // ds_read_b128
    return u.b;
}

__device__ __forceinline__ f32x4 mfma16(bf16x8 a, bf16x8 b, f32x4 c) {
    return __builtin_amdgcn_mfma_f32_16x16x32_bf16(a, b, c, 0, 0, 0);
}

// ---------------------------------------------------------------- fused casts
__global__ void cast3_kernel(const float* __restrict__ a, unsigned short* __restrict__ oa, int na4,
                             const float* __restrict__ b, unsigned short* __restrict__ ob, int nb4,
                             const float* __restrict__ c, unsigned short* __restrict__ oc) {
    int i = blockIdx.x * blockDim.x + threadIdx.x;
    const float* src; unsigned short* dst; int j;
    if (i < na4)            { src = a; dst = oa; j = i; }
    else if (i < na4 + nb4) { src = b; dst = ob; j = i - na4; }
    else                    { src = c; dst = oc; j = i - na4 - nb4; }
    f32x4 v = ((const f32x4*)src)[j];
    union { i32x2 i2; unsigned u[2]; } o;
    o.u[0] = pack2bf(v.x, v.y);
    o.u[1] = pack2bf(v.z, v.w);
    ((i32x2*)dst)[j] = o.i2;
}

// ---------------------------------------------------------------- GEMM1 (QKV)
// [4096,3072] = x[4096,1024] @ qkv_w^T + qkv_b, fused output routing:
//   col%192 <  64 (Q): *QSCALE -> qk[row*2048 + h*128 + part]
//   col%192 < 128 (K):          -> qk[row*2048 + h*128 + part]
//   col%192 >= 128 (V):         -> vT[bh][i][perm(s)]  (PV-slot order)
__global__ __launch_bounds__(256, 3)
void gemm_qkv_kernel(const unsigned short* __restrict__ A,
                     const unsigned short* __restrict__ B,
                     const float* __restrict__ bias,
                     unsigned short* __restrict__ qk,
                     unsigned short* __restrict__ vT,
                     int K) {
    __shared__ __align__(16) unsigned short As[128 * 64];
    __shared__ __align__(16) unsigned short Bs[128 * 64];

    const int tid  = threadIdx.x;
    const int wave = tid >> 6, lane = tid & 63;
    const int quad = lane >> 4, l16 = lane & 15;
    // XCD swizzle: 768 blocks = 8 XCDs x 96 (8 rows x 12 cols of tiles)
    const int flat = blockIdx.y * 24 + blockIdx.x;
    const int xcd = flat & 7, idx = flat >> 3;          // idx in 0..95
    const int row_blk = (xcd >> 1) * 8 + idx / 12;      // 0..31
    const int col_blk = (xcd & 1) * 12 + idx % 12;      // 0..23
    const int row0 = row_blk * 128, col0 = col_blk * 128;
    const int wr = (wave >> 1) * 64, wc = (wave & 1) * 64;

    f32x4 acc[4][4];
#pragma unroll
    for (int i = 0; i < 4; ++i)
#pragma unroll
        for (int j = 0; j < 4; ++j) acc[i][j] = (f32x4){0.f, 0.f, 0.f, 0.f};

    const int nkt = K >> 6;
    for (int kt = 0; kt < nkt; ++kt) {
        const int k0 = kt << 6;
#pragma unroll
        for (int i = 0; i < 4; ++i) {
            int p = i * 256 + tid;
            int r = p >> 3;
            int kc = (p & 7) ^ (r & 7);
            load_lds16(A + (size_t)(row0 + r) * K + k0 + kc * 8, &As[p * 8]);
        }
#pragma unroll
        for (int i = 0; i < 4; ++i) {
            int p = i * 256 + tid;
            int r = p >> 3;
            int kc = (p & 7) ^ (r & 7);
            load_lds16(B + (size_t)(col0 + r) * K + k0 + kc * 8, &Bs[p * 8]);
        }
        __syncthreads();

#pragma unroll
        for (int ks = 0; ks < 2; ++ks) {
            bf16x8 af[4], bfr[4];
#pragma unroll
            for (int rb = 0; rb < 4; ++rb) {
                int r_l  = wr + rb * 16 + l16;
                int phys = (ks * 4 + quad) ^ (l16 & 7);
                af[rb] = lds_read8(&As[r_l * 64 + phys * 8]);
            }
#pragma unroll
            for (int cb = 0; cb < 4; ++cb) {
                int r_l  = wc + cb * 16 + l16;
                int phys = (ks * 4 + quad) ^ (l16 & 7);
                bfr[cb] = lds_read8(&Bs[r_l * 64 + phys * 8]);
            }
#pragma unroll
            for (int rb = 0; rb < 4; ++rb)
#pragma unroll
                for (int cb = 0; cb < 4; ++cb)
                    acc[rb][cb] = mfma16(af[rb], bfr[cb], acc[rb][cb]);
        }
        __syncthreads();
    }

    // epilogue: C row = quad*4+reg, col = l16 (m89/m91 layout)
#pragma unroll
    for (int rb = 0; rb < 4; ++rb)
#pragma unroll
        for (int cb = 0; cb < 4; ++cb) {
            int col = col0 + wc + cb * 16 + l16;
            int h    = col / 192;
            int part = col - h * 192;
            float bv = bias[col];
            int row_b = row0 + wr + rb * 16 + quad * 4;
            float v[4];
#pragma unroll
            for (int reg = 0; reg < 4; ++reg) v[reg] = acc[rb][cb][reg] + bv;
            if (part < 128) {                  // Q or K -> qk row-major
                float sc = (part < 64) ? QSCALE_F : 1.0f;
                size_t base = (size_t)h * 128 + part;
#pragma unroll
                for (int reg = 0; reg < 4; ++reg)
                    qk[(size_t)(row_b + reg) * QK_STRIDE + base] = f2bf(v[reg] * sc);
            } else {                           // V -> vT[bh][i][perm(s)], 8B packed
                int i  = part - 128;
                int b  = row_b >> 11;
                int s0 = row_b & 2047;
                // key-permutation within 128-tile: slot=(c>>1)*32+q*8+(c&1)*4+r
                int kk = s0 & 127;
                int cc = kk >> 4, qq = (kk >> 2) & 3;
                int sp = (s0 & ~127) | ((cc >> 1) << 5) | (qq << 3) | ((cc & 1) << 2);
                i32x2 pk;
                pk.x = (int)pack2bf(v[0], v[1]);
                pk.y = (int)pack2bf(v[2], v[3]);
                *(i32x2*)&vT[(((size_t)(b * 16 + h)) * 64 + i) * SEQ + sp] = pk;
            }
        }
}

// ---------------------------------------------------------------- GEMM2 128x64
// out[4096,1024] = attn @ out_w^T + out_b.  512 blocks = 2/CU exact.
__global__ __launch_bounds__(256, 2)
void gemm2_kernel(const unsigned short* __restrict__ A,
                  const unsigned short* __restrict__ B,
                  const float* __restrict__ bias,
                  float* __restrict__ C, int M, int N, int K) {
    __shared__ __align__(16) unsigned short As[128 * 64];   // 16KB
    __shared__ __align__(16) unsigned short Bs[64 * 64];    //  8KB

    const int tid  = threadIdx.x;
    const int wave = tid >> 6, lane = tid & 63;
    const int quad = lane >> 4, l16 = lane & 15;
    // XCD swizzle: 512 blocks = 8 XCDs x 64 (8 rows x 8 cols of tiles)
    const int flat = blockIdx.y * 16 + blockIdx.x;
    const int xcd = flat & 7, idx = flat >> 3;          // idx in 0..63
    const int row_blk = (xcd >> 1) * 8 + (idx >> 3);    // 0..31
    const int col_blk = (xcd & 1) * 8 + (idx & 7);      // 0..15
    const int row0 = row_blk * 128, col0 = col_blk * 64;
    const int wr = wave * 32;

    f32x4 acc[2][4];
#pragma unroll
    for (int i = 0; i < 2; ++i)
#pragma unroll
        for (int j = 0; j < 4; ++j) acc[i][j] = (f32x4){0.f, 0.f, 0.f, 0.f};

    const int nkt = K >> 6;
    for (int kt = 0; kt < nkt; ++kt) {
        const int k0 = kt << 6;
#pragma unroll
        for (int i = 0; i < 4; ++i) {
            int p = i * 256 + tid;
            int r = p >> 3;
            int kc = (p & 7) ^ (r & 7);
            load_lds16(A + (size_t)(row0 + r) * K + k0 + kc * 8, &As[p * 8]);
        }
#pragma unroll
        for (int i = 0; i < 2; ++i) {
            int p = i * 256 + tid;
            int r = p >> 3;
            int kc = (p & 7) ^ (r & 7);
            load_lds16(B + (size_t)(col0 + r) * K + k0 + kc * 8, &Bs[p * 8]);
        }
        __syncthreads();

#pragma unroll
        for (int ks = 0; ks < 2; ++ks) {
            bf16x8 af[2], bfr[4];
#pragma unroll
            for (int rb = 0; rb < 2; ++rb) {
                int r_l  = wr + rb * 16 + l16;
                int phys = (ks * 4 + quad) ^ (l16 & 7);
                af[rb] = lds_read8(&As[r_l * 64 + phys * 8]);
            }
#pragma unroll
            for (int cb = 0; cb < 4; ++cb) {
                int r_l  = cb * 16 + l16;
                int phys = (ks * 4 + quad) ^ (l16 & 7);
                bfr[cb] = lds_read8(&Bs[r_l * 64 + phys * 8]);
            }
#pragma unroll
            for (int rb = 0; rb < 2; ++rb)
#pragma unroll
                for (int cb = 0; cb < 4; ++cb)
                    acc[rb][cb] = mfma16(af[rb], bfr[cb], acc[rb][cb]);
        }
        __syncthreads();
    }

#pragma unroll
    for (int rb = 0; rb < 2; ++rb)
#pragma unroll
        for (int cb = 0; cb < 4; ++cb) {
            int col = col0 + cb * 16 + l16;
            float bv = bias[col];
#pragma unroll
            for (int reg = 0; reg < 4; ++reg) {
                int row = row0 + wr + rb * 16 + quad * 4 + reg;
                C[(size_t)row * N + col] = acc[rb][cb][reg] + bv;
            }
        }
}

// ---------------------------------------------------------------- attention
// R19 attn (49.9-53.6us band): in-reg P (V-key-permute), K/V dbuf,
// counted vmcnt(4), hoisted softmax reduction.

#define STAGE_KV(BUF) do {                                                     \
    load_lds16(kg[0], lk[0] + (BUF) * 8192); kg[0] += 128 * QK_STRIDE;         \
    load_lds16(kg[1], lk[1] + (BUF) * 8192); kg[1] += 128 * QK_STRIDE;         \
    load_lds16(vg[0], lv[0] + (BUF) * 8192); vg[0] += 128;                     \
    load_lds16(vg[1], lv[1] + (BUF) * 8192); vg[1] += 128;                     \
} while (0)

#define COMPUTE_TILE(BUF) do {                                                 \
    constexpr int KO_ = (BUF) * 8192;                                          \
    f32x4 s[8];                                                                \
    _Pragma("unroll") for (int cb = 0; cb < 8; ++cb)                           \
        s[cb] = (f32x4){0.f, 0.f, 0.f, 0.f};                                   \
    __builtin_amdgcn_s_setprio(1);                                             \
    _Pragma("unroll") for (int cb = 0; cb < 8; ++cb) {                         \
        bf16x8 kf0 = lds_read8(Kb0 + KO_ + cb * 1024);                         \
        s[cb] = mfma16(kf0, qf[0], s[cb]);                                     \
    }                                                                          \
    _Pragma("unroll") for (int cb = 0; cb < 8; ++cb) {                         \
        bf16x8 kf1 = lds_read8(Kb1 + KO_ + cb * 1024);                         \
        s[cb] = mfma16(kf1, qf[1], s[cb]);                                     \
    }                                                                          \
    __builtin_amdgcn_s_setprio(0);                                             \
    _Pragma("unroll") for (int cb = 0; cb < 8; ++cb)                           \
        _Pragma("unroll") for (int r = 0; r < 4; ++r)                          \
            s[cb][r] = EXP2F(s[cb][r]);                                        \
    {                                                                          \
        f32x4 t0 = s[0] + s[1], t1 = s[2] + s[3];                              \
        f32x4 t2 = s[4] + s[5], t3 = s[6] + s[7];                              \
        t0 += t1; t2 += t3;                                                    \
        lsum += t0 + t2;                                                       \
    }                                                                          \
    __builtin_amdgcn_s_setprio(1);                                             \
    _Pragma("unroll") for (int ks2 = 0; ks2 < 4; ++ks2) {                      \
        union { i32x4 i; bf16x8 b; } pu;                                       \
        pu.i.x = (int)pack2bf(s[2 * ks2][0], s[2 * ks2][1]);                   \
        pu.i.y = (int)pack2bf(s[2 * ks2][2], s[2 * ks2][3]);                   \
        pu.i.z = (int)pack2bf(s[2 * ks2 + 1][0], s[2 * ks2 + 1][1]);           \
        pu.i.w = (int)pack2bf(s[2 * ks2 + 1][2], s[2 * ks2 + 1][3]);           \
        bf16x8 pf = pu.b;                                                      \
        _Pragma("unroll") for (int ib = 0; ib < 4; ++ib) {                     \
            bf16x8 vf = lds_read8(Vb[ks2] + KO_ + ib * 2048);                  \
            o[ib] = mfma16(pf, vf, o[ib]);                                     \
        }                                                                      \
    }                                                                          \
    __builtin_amdgcn_s_setprio(0);                                             \
} while (0)

__global__ __launch_bounds__(512, 4)
void attn_kernel(const unsigned short* __restrict__ qk,
                 const unsigned short* __restrict__ vT,
                 unsigned short* __restrict__ attn) {
    __shared__ __align__(16) unsigned short Ks[2][128 * 64]; // 32KB [buf][key][dim]
    __shared__ __align__(16) unsigned short Vs[2][64 * 128]; // 32KB [buf][i][slot]

    const int tid  = threadIdx.x;
    const int wave = tid >> 6, lane = tid & 63;
    const int quad = lane >> 4, l16 = lane & 15;

    // T1: XCD-aware remap (R9-proven).
    const int flat = blockIdx.y * 16 + blockIdx.x;
    const int swz  = (flat & 7) * 64 + (flat >> 3);
    const int bh = swz >> 4;
    const int b = bh >> 4, h = bh & 15;
    const int q0 = (swz & 15) * 128;
    const size_t rowbase = (size_t)b * SEQ;
    const int qtok = q0 + wave * 16 + l16;

    // per-lane LDS bases (shorts); loop vars become immediate offsets
    const int sw3 = l16 & 7;
    const unsigned short* Kb0 = &Ks[0][l16 * 64 + ((quad ^ sw3) * 8)];         // ks=0, +cb*1024
    const unsigned short* Kb1 = &Ks[0][l16 * 64 + (((4 + quad) ^ sw3) * 8)];   // ks=1
    const unsigned short* Vb[4] = {                                            // ks2=0..3, +ib*2048
        &Vs[0][l16 * 128 + (((0 * 4 + quad) ^ l16) * 8)],
        &Vs[0][l16 * 128 + (((1 * 4 + quad) ^ l16) * 8)],
        &Vs[0][l16 * 128 + (((2 * 4 + quad) ^ l16) * 8)],
        &Vs[0][l16 * 128 + (((3 * 4 + quad) ^ l16) * 8)] };

    // staging addresses (hoisted; advance by constant per tile)
    const unsigned short* kg[2]; unsigned short* lk[2];
    const unsigned short* vg[2]; unsigned short* lv[2];
#pragma unroll
    for (int i = 0; i < 2; ++i) {
        int p = i * 512 + tid;
        { int r = p >> 3; int kc = (p & 7) ^ (r & 7);
          kg[i] = qk + (rowbase) * QK_STRIDE + h * 128 + 64 + (size_t)r * QK_STRIDE + kc * 8;
          lk[i] = &Ks[0][p * 8]; }
        { int r = p >> 4; int c = (p & 15) ^ (r & 15);
          vg[i] = vT + (size_t)bh * 64 * SEQ + (size_t)r * SEQ + c * 8;
          lv[i] = &Vs[0][p * 8]; }
    }

    // Q fragments (B-operand: n=l16=query, k=quad*8+j), pre-scaled in GEMM1
    bf16x8 qf[2];
#pragma unroll
    for (int ks = 0; ks < 2; ++ks) {
        const unsigned short* p =
            qk + (rowbase + qtok) * QK_STRIDE + h * 128 + ks * 32 + quad * 8;
        union { i32x4 i; bf16x8 b; } u;
        u.i = *(const i32x4*)p;
        qf[ks] = u.b;
    }

    f32x4 o[4];
#pragma unroll
    for (int ib = 0; ib < 4; ++ib) o[ib] = (f32x4){0.f, 0.f, 0.f, 0.f};
    f32x4 lsum = (f32x4){0.f, 0.f, 0.f, 0.f};

    // ---- pipelined K-loop: 2 tiles/iter, compile-time buffer indices
    STAGE_KV(0);
#pragma unroll 1
    for (int kt = 0; kt < SEQ / 128; kt += 2) {
        STAGE_KV(1);
        __asm__ volatile("s_waitcnt vmcnt(4)" ::: "memory");
        __builtin_amdgcn_s_barrier();
        COMPUTE_TILE(0);
        __builtin_amdgcn_s_barrier();
        if (kt + 2 < SEQ / 128) {
            STAGE_KV(0);
            __asm__ volatile("s_waitcnt vmcnt(4)" ::: "memory");
        } else {
            __asm__ volatile("s_waitcnt vmcnt(0)" ::: "memory");
        }
        __builtin_amdgcn_s_barrier();
        COMPUTE_TILE(1);
        __builtin_amdgcn_s_barrier();
    }

    // ---- softmax denominator: horizontal + cross-quad reduce (once)
    float l_p = (lsum[0] + lsum[1]) + (lsum[2] + lsum[3]);
    l_p += __shfl_xor(l_p, 16);
    l_p += __shfl_xor(l_p, 32);

    // ---- normalize, write attn[token][h*64+i] (bf16). O rows = quad*4+r.
    float il[4];
#pragma unroll
    for (int r = 0; r < 4; ++r) il[r] = 1.0f / __shfl(l_p, quad * 4 + r);
#pragma unroll
    for (int ib = 0; ib < 4; ++ib)
#pragma unroll
        for (int r = 0; r < 4; ++r) {
            int t = q0 + wave * 16 + quad * 4 + r;
            attn[(rowbase + t) * E_DIM + h * 64 + ib * 16 + l16] =
                f2bf(o[ib][r] * il[r]);
        }
}

// ---------------------------------------------------------------- launch
extern "C" void kernel_launch(void* const* d_in, const int* in_sizes, int n_in,
                              void* d_out, int out_size, void* d_ws, size_t ws_size,
                              hipStream_t stream) {
    const float* x     = (const float*)d_in[0];   // [2,2048,1024]
    const float* qkv_w = (const float*)d_in[1];   // [3072,1024]
    const float* qkv_b = (const float*)d_in[2];   // [3072]
    const float* out_w = (const float*)d_in[3];   // [1024,1024]
    const float* out_b = (const float*)d_in[4];   // [1024]

    char* ws = (char*)d_ws;
    unsigned short* xb   = (unsigned short*)(ws);               //  8 MB
    unsigned short* wqkv = (unsigned short*)(ws + 8388608);     //  6 MB
    unsigned short* wout = (unsigned short*)(ws + 14680064);    //  2 MB
    unsigned short* qk   = (unsigned short*)(ws + 16777216);    // 16 MB [4096][2048]
    unsigned short* attn = (unsigned short*)(ws + 33554432);    //  8 MB
    unsigned short* vT   = (unsigned short*)(ws + 41943040);    //  8 MB [32][64][2048]
    // total 48 MB

    // fused casts: x (1048576 f32x4), qkv_w (786432), out_w (262144)
    cast3_kernel<<<8192, 256, 0, stream>>>(x, xb, 1048576,
                                           qkv_w, wqkv, 786432,
                                           out_w, wout);

    // QKV projection with fused routing: Q,K -> qk (Q scaled); V -> vT (permuted)
    gemm_qkv_kernel<<<dim3(24, 32), 256, 0, stream>>>(
        xb, wqkv, qkv_b, qk, vT, E_DIM);

    // flash attention -> attn [4096, 1024] bf16 (128q/512thr, in-reg P, dbuf)
    attn_kernel<<<dim3(16, 32), 512, 0, stream>>>(qk, vT, attn);

    // out = attn @ out_w^T + out_b   [4096, 1024] fp32 (128x64 tiles, 512 blocks)
    gemm2_kernel<<<dim3(16, 32), 256, 0, stream>>>(
        attn, wout, out_b, (float*)d_out, TOK, E_DIM, E_DIM);
}